// Round 9
// baseline (434.958 us; speedup 1.0000x reference)
//
#include <hip/hip_runtime.h>
#include <hip/hip_cooperative_groups.h>
#include <math.h>

namespace cg = cooperative_groups;

typedef unsigned int u32;
typedef unsigned long long u64;

#define NANCH   36864
#define PRE     6000
#define POST    2000
#define NWORDS  94        // ceil(6000/64)
#define ROWSP   6016      // padded rows per mask column
#define NBLK    94
#define NTHR    1024
#define GSZ     (NBLK * NTHR)   // 96256

// ---------------- workspace layout (bytes) ----------------
#define OFF_PROPS   ((size_t)0)          // 36864*16 = 589824
#define OFF_SV      ((size_t)589824)     // 36864*8  -> 884736
#define OFF_SORTED  ((size_t)884736)     // 6016*8   -> 932864
#define OFF_SEL     ((size_t)932864)     // 36864*8  -> 1227776
#define OFF_MASKT   ((size_t)1227776)    // 94*6016*8 = 4524032 -> 5751808
                                         // (also aliases rank0 u32[36864] during P3/P4 — disjoint lifetime)
#define OFF_CTRL    ((size_t)5751808)    // 256
#define OFF_H1      ((size_t)5752064)    // 1025*4

// base anchors for base_size=16, ratios(0.5,1,2), scales(8,16,32) — np.round (banker's) applied
__device__ __constant__ float BA[9][4] = {
  {-84.f,-40.f,99.f,55.f},   {-176.f,-88.f,191.f,103.f}, {-360.f,-184.f,375.f,199.f},
  {-56.f,-56.f,71.f,71.f},   {-120.f,-120.f,135.f,135.f},{-248.f,-248.f,263.f,263.f},
  {-36.f,-80.f,51.f,95.f},   {-80.f,-168.f,95.f,183.f},  {-168.f,-344.f,183.f,359.f}};

// bin over key bits [31:13]: 1024 bins cover scores [0.5,1) exactly (monotone in key);
// bin 0 = everything below (incl. invalid key==0). Selection stays EXACT: we take the
// whole union of bins >= chosen and rank it all-pairs (keys are distinct).
__device__ __forceinline__ u32 key_bin(u32 key) {
  if (key < 0xBF000000u) return 0u;
  u32 b = ((key >> 13) - 0x5F800u) + 1u;
  return b > 1024u ? 1024u : b;
}

__device__ __forceinline__ u64 rl64(u64 v, int lane) {
  u32 lo = (u32)__builtin_amdgcn_readlane((int)(u32)v, lane);
  u32 hi = (u32)__builtin_amdgcn_readlane((int)(u32)(v >> 32), lane);
  return ((u64)hi << 32) | (u64)lo;
}

__global__ void __launch_bounds__(1024) fused_k(const float* __restrict__ deltas,
                                                const float* __restrict__ scores,
                                                const int* __restrict__ imw_p,
                                                const int* __restrict__ imh_p,
                                                char* __restrict__ ws,
                                                float* __restrict__ out) {
  #pragma clang fp contract(off)
  float4* props  = (float4*)(ws + OFF_PROPS);
  u64*    svals  = (u64*)(ws + OFF_SV);
  u64*    sorted = (u64*)(ws + OFF_SORTED);
  u64*    sel    = (u64*)(ws + OFF_SEL);
  u64*    maskT  = (u64*)(ws + OFF_MASKT);
  u32*    rank0  = (u32*)(ws + OFF_MASKT);   // alias: used P3/P4, overwritten by mask in P5
  u32*    ctrl   = (u32*)(ws + OFF_CTRL);
  u32*    h1     = (u32*)(ws + OFF_H1);

  cg::grid_group grid = cg::this_grid();
  const int t = threadIdx.x;
  const int b = blockIdx.x;
  const int gid = b * NTHR + t;

  __shared__ u64 SJ[1024];
  __shared__ u32 Lchosen;
  __shared__ u64 Lrem[NWORDS];
  __shared__ u64 Ldiag[64];
  __shared__ u64 Lkb[NWORDS];
  __shared__ u64 LkA;
  __shared__ int Lstop;
  __shared__ u32 Lpre[NWORDS];

  // ---------------- P0: zero h1 / ctrl / rank0 ----------------
  if (gid < 1025) h1[gid] = 0u;
  if (gid < 64) ctrl[gid] = 0u;
  if (gid < NANCH) rank0[gid] = 0u;
  grid.sync();

  // ---------------- P1: decode + fused histogram ----------------
  if (gid < NANCH) {
    int i = gid;
    int a = i % 9;
    int pix = i / 9;
    int x = pix & 63, y = pix >> 6;

    float sc = scores[(9 + a) * 4096 + pix];
    float d0 = deltas[(a * 4 + 0) * 4096 + pix];
    float d1 = deltas[(a * 4 + 1) * 4096 + pix];
    float d2 = deltas[(a * 4 + 2) * 4096 + pix];
    float d3 = deltas[(a * 4 + 3) * 4096 + pix];

    float gx = (float)(x * 16), gy = (float)(y * 16);
    float ax1 = gx + BA[a][0], ay1 = gy + BA[a][1];
    float ax2 = gx + BA[a][2], ay2 = gy + BA[a][3];
    float aw = ax2 - ax1 + 1.0f, ah = ay2 - ay1 + 1.0f;
    float acx = ax1 + 0.5f * aw, acy = ay1 + 0.5f * ah;

    float pcx = d0 * aw + acx;
    float pcy = d1 * ah + acy;
    float pw = (float)exp((double)d2) * aw;   // f64 exp -> correctly-rounded f32
    float ph = (float)exp((double)d3) * ah;

    float imw1 = (float)imw_p[0] - 1.0f, imh1 = (float)imh_p[0] - 1.0f;
    float x1 = fminf(fmaxf(pcx - 0.5f * pw, 0.0f), imw1);
    float y1 = fminf(fmaxf(pcy - 0.5f * ph, 0.0f), imh1);
    float x2 = fminf(fmaxf(pcx + 0.5f * pw, 0.0f), imw1);
    float y2 = fminf(fmaxf(pcy + 0.5f * ph, 0.0f), imh1);
    props[i] = make_float4(x1, y1, x2, y2);

    float thresh = 16.0f * ((float)imh_p[0] / (float)imw_p[0]);
    bool keep = (x2 - x1 + 1.0f >= thresh) && (y2 - y1 + 1.0f >= thresh);
    u32 key = keep ? (__float_as_uint(sc) | 0x80000000u) : 0u;  // scores >= 0
    svals[i] = ((u64)key << 32) | (u64)(0xFFFFFFFFu - (u32)i);  // distinct; desc == top_k order
    u32 bin = key_bin(key);
    if (bin) atomicAdd(&h1[bin], 1u);
  }
  grid.sync();

  // ---------------- P2: compact union (chosen recomputed per block) + zero out ----------------
  if (t < 64) {
    int l = t;
    u32 loc[16], suf[16];
    #pragma unroll
    for (int k = 0; k < 16; ++k) loc[k] = h1[1 + l * 16 + k];
    u32 acc = 0;
    #pragma unroll
    for (int k = 15; k >= 0; --k) { acc += loc[k]; suf[k] = acc; }
    u32 sfx = acc;
    for (int off = 1; off < 64; off <<= 1) {
      u32 o = __shfl_down(sfx, off);
      if (l + off < 64) sfx += o;
    }
    u32 S_above = sfx - acc;           // sum over lanes > l
    u64 mball = __ballot(suf[0] + S_above >= (u32)PRE);
    if (mball == 0ULL) { if (l == 0) Lchosen = 0u; }
    else {
      int L = 63 - __builtin_clzll(mball);
      if (l == L) {
        int kk = 0;
        for (int k = 15; k >= 0; --k)
          if (suf[k] + S_above >= (u32)PRE) { kk = k; break; }
        Lchosen = (u32)(1 + 16 * L + kk);
      }
    }
  }
  __syncthreads();
  if (gid < 12000) out[gid] = 0.0f;    // blob + scores zero-fill
  {
    u32 chosen = Lchosen;
    if (gid < NANCH) {
      u64 v = svals[gid];
      if (key_bin((u32)(v >> 32)) >= chosen) {
        u32 p = atomicAdd(&ctrl[6], 1u);
        sel[p] = v;
      }
    }
  }
  grid.sync();

  // ---------------- P3: all-pairs rank partials (blocks: 6 i-chunks x 15 j-chunks) --------
  u32 n = ctrl[6];                     // n >= PRE by construction (or n = NANCH in fallback)
  if (b < 90) {
    const int ic = b / 15, jc = b % 15;
    const u32 chunk = (n + 14u) / 15u;
    const u32 j0 = jc * chunk, j1 = min(j0 + chunk, n);
    const u32 base_i = (u32)(ic * 1024 + t);
    u64 vi[6]; u32 cnt[6]; int ni = 0;
    for (u32 ii = base_i; ii < n && ni < 6; ii += 6144u) { vi[ni] = sel[ii]; cnt[ni] = 0; ++ni; }
    for (u32 jb = j0; jb < j1; jb += 1024u) {
      __syncthreads();
      if (jb + (u32)t < j1) SJ[t] = sel[jb + t];
      __syncthreads();
      u32 m = min(1024u, j1 - jb);
      for (u32 j = 0; j < m; ++j) {
        u64 s = SJ[j];
        for (int q = 0; q < ni; ++q) cnt[q] += (u32)(s > vi[q]);
      }
    }
    for (int q = 0; q < ni; ++q)
      if (cnt[q]) atomicAdd(&rank0[base_i + (u32)q * 6144u], cnt[q]);
  }
  grid.sync();

  // ---------------- P4: scatter sorted[rank] = sel (ranks < PRE are global ranks) ---------
  for (u32 ii = (u32)gid; ii < n; ii += (u32)GSZ) {
    u32 r = rank0[ii];
    if (r < (u32)PRE) sorted[r] = sel[ii];
  }
  grid.sync();

  // ---------------- P5: suppression bitmask (block b = row band ib=b; shfl col boxes) -----
  {
    const int ib = b;
    const int sub = t >> 6, lane = t & 63;
    const int i = ib * 64 + lane;
    float4 bb = make_float4(0.f, 0.f, 0.f, 0.f);
    float ai = 1.0f;
    const bool rowok = (i < PRE);
    if (rowok) {
      u64 v = sorted[i];
      bb = props[0xFFFFu - ((u32)v & 0xFFFFu)];
      ai = (bb.z - bb.x + 1.0f) * (bb.w - bb.y + 1.0f);
    }
    for (int jb = ib + sub; jb < NWORDS; jb += 16) {
      int jj = jb * 64 + lane;
      float4 cl = make_float4(0.f, 0.f, 0.f, 0.f);
      if (jj < PRE) {
        u64 v = sorted[jj];
        cl = props[0xFFFFu - ((u32)v & 0xFFFFu)];
      }
      u64 bits = 0ULL;
      for (int j = 0; j < 64; ++j) {
        float cx1 = __shfl(cl.x, j), cy1 = __shfl(cl.y, j);
        float cx2 = __shfl(cl.z, j), cy2 = __shfl(cl.w, j);
        float aj = (cx2 - cx1 + 1.0f) * (cy2 - cy1 + 1.0f);
        float iw = fmaxf(fminf(bb.z, cx2) - fmaxf(bb.x, cx1) + 1.0f, 0.0f);
        float ih = fmaxf(fminf(bb.w, cy2) - fmaxf(bb.y, cy1) + 1.0f, 0.0f);
        float inter = iw * ih;
        float iou = inter / (ai + aj - inter);
        bits |= ((u64)(iou > 0.7f)) << j;
      }
      if (rowok) maskT[(size_t)jb * ROWSP + i] = bits;
    }
  }
  grid.sync();

  if (b != 0) return;

  // ---------------- P6 (block 0 only): greedy NMS scan + fused output scatter -------------
  {
    const int g = t & 7;                 // row octet within current word
    const int w = t >> 3;                // column owned (if < 94)
    const bool loader = (w < NWORDS);
    u64 rv = 0;
    u64 A0[8], A1[8], A2[8];
    int kept = 0;
    if (t < NWORDS) { Lrem[t] = 0ULL; Lkb[t] = 0ULL; }
    if (t == 0) Lstop = 0;
    __syncthreads();
    for (int r = t; r < PRE; r += NTHR)
      if ((u32)(sorted[r] >> 32) == 0u)
        atomicOr((unsigned long long*)&Lrem[r >> 6], 1ULL << (r & 63));
    if (t == 0)
      atomicOr((unsigned long long*)&Lrem[NWORDS - 1],
               ~((1ULL << (PRE - (NWORDS - 1) * 64)) - 1ULL));
    __syncthreads();

#define ISSUE(bb, BUF) \
    if ((bb) < NWORDS && loader && w >= (bb)) { \
      const u64* p_ = maskT + (size_t)w * ROWSP + (bb) * 64 + g * 8; \
      _Pragma("unroll") \
      for (int k = 0; k < 8; ++k) BUF[k] = p_[k]; \
    }

#define STEP(bb, BUF) { \
    if (w == (bb)) {                     /* 8 publishers */ \
      atomicOr((u32*)&Lrem[(bb)], (u32)rv); \
      atomicOr(((u32*)&Lrem[(bb)]) + 1, (u32)(rv >> 32)); \
      _Pragma("unroll") \
      for (int k = 0; k < 8; ++k) Ldiag[g * 8 + k] = BUF[k]; \
    } \
    __syncthreads();                     /* X: diag + final Lrem[bb] visible */ \
    if (t < 64) { \
      u64 dgl = Ldiag[t]; \
      u64 avail = ~Lrem[(bb)]; \
      u64 kb = 0; \
      while (avail) { \
        int i_ = __builtin_ctzll(avail); \
        kb |= 1ULL << i_; \
        avail &= ~rl64(dgl, i_) & ~((2ULL << i_) - 1ULL); /* 2<<63 wraps -> 0 */ \
      } \
      if (t == 0) { \
        Lkb[(bb)] = kb; LkA = kb; \
        kept += (int)__popcll(kb); \
        if (kept >= POST) Lstop = 1; \
      } \
    } \
    __syncthreads();                     /* Y: kb + stop visible */ \
    if (loader && w > (bb)) { \
      u64 kb_ = LkA; \
      _Pragma("unroll") \
      for (int k = 0; k < 8; ++k) { \
        u64 bit_ = (kb_ >> (g * 8 + k)) & 1ULL; \
        rv |= (0ULL - bit_) & BUF[k]; \
      } \
    } \
    ISSUE((bb) + 3, BUF) \
    if (Lstop) break; }

    ISSUE(0, A0)
    ISSUE(1, A1)
    ISSUE(2, A2)
    for (int bb = 0; bb < NWORDS; bb += 3) {
      STEP(bb, A0)
      if (bb + 1 < NWORDS) STEP(bb + 1, A1)
      if (bb + 2 < NWORDS) STEP(bb + 2, A2)
    }
#undef ISSUE
#undef STEP

    __syncthreads();
    if (t == 0) {
      u32 run = 0;
      for (int w2 = 0; w2 < NWORDS; ++w2) { Lpre[w2] = run; run += (u32)__popcll(Lkb[w2]); }
    }
    __syncthreads();
    for (int i = t; i < PRE; i += NTHR) {
      u64 word = Lkb[i >> 6];
      if ((word >> (i & 63)) & 1ULL) {
        u32 rank = Lpre[i >> 6] + (u32)__popcll(word & ((1ULL << (i & 63)) - 1ULL));
        if (rank < POST) {
          u64 v = sorted[i];
          float4 bx = props[0xFFFFu - ((u32)v & 0xFFFFu)];
          out[rank * 5 + 1] = bx.x;
          out[rank * 5 + 2] = bx.y;
          out[rank * 5 + 3] = bx.z;
          out[rank * 5 + 4] = bx.w;
          out[10000 + rank] = __uint_as_float((u32)(v >> 32) & 0x7FFFFFFFu);  // col 0 stays 0
        }
      }
    }
  }
}

extern "C" void kernel_launch(void* const* d_in, const int* in_sizes, int n_in,
                              void* d_out, int out_size, void* d_ws, size_t ws_size,
                              hipStream_t stream) {
  const float* deltas = (const float*)d_in[0];
  const float* scores = (const float*)d_in[1];
  const int* imw = (const int*)d_in[2];
  const int* imh = (const int*)d_in[3];
  char* ws = (char*)d_ws;
  float* out = (float*)d_out;

  void* args[] = { (void*)&deltas, (void*)&scores, (void*)&imw, (void*)&imh,
                   (void*)&ws, (void*)&out };
  hipLaunchCooperativeKernel((const void*)fused_k, dim3(NBLK), dim3(NTHR),
                             args, 0, stream);
}

// Round 10
// 367.950 us; speedup vs baseline: 1.1821x; 1.1821x over previous
//
#include <hip/hip_runtime.h>
#include <math.h>

typedef unsigned int u32;
typedef unsigned long long u64;

#define NANCH   36864
#define PRE     6000
#define POST    2000
#define NWORDS  94        // ceil(6000/64), even
#define NSTEP   47        // 2 words per step
#define ROWSP   6016      // padded rows per mask column

// ---------------- workspace layout (bytes) ----------------
#define OFF_PROPS   ((size_t)0)                    // 36864*16 = 589824
#define OFF_SV      ((size_t)589824)               // 36864*8  = 294912 -> 884736
#define OFF_SORTED  ((size_t)884736)               // 6016*8   = 48128  -> 932864
#define OFF_SEL     ((size_t)932864)               // 36864*8  = 294912 (fallback-sized) -> 1227776
#define OFF_MASKT   ((size_t)1227776)              // 94*6016*8 = 4524032 -> 5751808 (column-major: maskT[w*6016+row])
#define OFF_CTRL    ((size_t)5751808)              // 256  (ctrl[6] zeroed by decode)
#define OFF_H1      ((size_t)5752064)              // 1025*4 = 4100 (memset target)

// base anchors for base_size=16, ratios(0.5,1,2), scales(8,16,32) — np.round (banker's) applied
__device__ __constant__ float BA[9][4] = {
  {-84.f,-40.f,99.f,55.f},   {-176.f,-88.f,191.f,103.f}, {-360.f,-184.f,375.f,199.f},
  {-56.f,-56.f,71.f,71.f},   {-120.f,-120.f,135.f,135.f},{-248.f,-248.f,263.f,263.f},
  {-36.f,-80.f,51.f,95.f},   {-80.f,-168.f,95.f,183.f},  {-168.f,-344.f,183.f,359.f}};

// bin over key bits [31:13]: 1024 bins cover scores [0.5,1) exactly (monotone in key);
// bin 0 = everything below (incl. invalid key==0). Selection stays EXACT: we take the
// whole union of bins >= chosen and rank it all-pairs (keys are distinct).
__device__ __forceinline__ u32 key_bin(u32 key) {
  if (key < 0xBF000000u) return 0u;
  u32 b = ((key >> 13) - 0x5F800u) + 1u;
  return b > 1024u ? 1024u : b;
}

// ---------------- 1) decode (+ fused 1024-bin histogram; bin 0 not counted) ----------------
__global__ void decode_k(const float* __restrict__ deltas, const float* __restrict__ scores,
                         const int* __restrict__ imw_p, const int* __restrict__ imh_p,
                         float4* __restrict__ props, u64* __restrict__ sortvals,
                         u32* __restrict__ h1, u32* __restrict__ ctrl) {
  #pragma clang fp contract(off)
  if (threadIdx.x == 0) ctrl[6] = 0u;   // all blocks write 0 before compact launch
  int i = blockIdx.x * 256 + threadIdx.x;
  if (i >= NANCH) return;
  int a = i % 9;
  int pix = i / 9;
  int x = pix & 63, y = pix >> 6;

  float sc = scores[(9 + a) * 4096 + pix];
  float d0 = deltas[(a * 4 + 0) * 4096 + pix];
  float d1 = deltas[(a * 4 + 1) * 4096 + pix];
  float d2 = deltas[(a * 4 + 2) * 4096 + pix];
  float d3 = deltas[(a * 4 + 3) * 4096 + pix];

  float gx = (float)(x * 16), gy = (float)(y * 16);
  float ax1 = gx + BA[a][0], ay1 = gy + BA[a][1];
  float ax2 = gx + BA[a][2], ay2 = gy + BA[a][3];
  float aw = ax2 - ax1 + 1.0f, ah = ay2 - ay1 + 1.0f;
  float acx = ax1 + 0.5f * aw, acy = ay1 + 0.5f * ah;

  float pcx = d0 * aw + acx;
  float pcy = d1 * ah + acy;
  float pw = (float)exp((double)d2) * aw;   // f64 exp -> correctly-rounded f32
  float ph = (float)exp((double)d3) * ah;

  float imw1 = (float)imw_p[0] - 1.0f, imh1 = (float)imh_p[0] - 1.0f;
  float x1 = fminf(fmaxf(pcx - 0.5f * pw, 0.0f), imw1);
  float y1 = fminf(fmaxf(pcy - 0.5f * ph, 0.0f), imh1);
  float x2 = fminf(fmaxf(pcx + 0.5f * pw, 0.0f), imw1);
  float y2 = fminf(fmaxf(pcy + 0.5f * ph, 0.0f), imh1);
  props[i] = make_float4(x1, y1, x2, y2);

  float thresh = 16.0f * ((float)imh_p[0] / (float)imw_p[0]);
  bool keep = (x2 - x1 + 1.0f >= thresh) && (y2 - y1 + 1.0f >= thresh);
  u32 key = keep ? (__float_as_uint(sc) | 0x80000000u) : 0u;  // scores >= 0
  sortvals[i] = ((u64)key << 32) | (u64)(0xFFFFFFFFu - (u32)i); // distinct; desc order == top_k order
  u32 bin = key_bin(key);
  if (bin) atomicAdd(&h1[bin], 1u);
}

// ---------------- 2) compact the union (bins >= chosen); chosen recomputed per block ------
__global__ void compact_k(const u64* __restrict__ sv, const u32* __restrict__ h1,
                          u32* __restrict__ ctrl, u64* __restrict__ sel) {
  __shared__ u32 Lchosen;
  int t = threadIdx.x;
  if (t < 64) {                        // wave 0: recompute chosen (largest bin with suffix >= PRE)
    int l = t;
    u32 loc[16], suf[16];
    #pragma unroll
    for (int k = 0; k < 16; ++k) loc[k] = h1[1 + l * 16 + k];
    u32 acc = 0;
    #pragma unroll
    for (int k = 15; k >= 0; --k) { acc += loc[k]; suf[k] = acc; }
    u32 sfx = acc;
    for (int off = 1; off < 64; off <<= 1) {
      u32 o = __shfl_down(sfx, off);
      if (l + off < 64) sfx += o;
    }
    u32 S_above = sfx - acc;           // sum over lanes > l
    u64 mball = __ballot(suf[0] + S_above >= (u32)PRE);
    if (mball == 0ULL) { if (l == 0) Lchosen = 0u; }
    else {
      int L = 63 - __builtin_clzll(mball);
      if (l == L) {
        int kk = 0;
        for (int k = 15; k >= 0; --k)
          if (suf[k] + S_above >= (u32)PRE) { kk = k; break; }
        Lchosen = (u32)(1 + 16 * L + kk);
      }
    }
  }
  __syncthreads();
  u32 chosen = Lchosen;
  int i = blockIdx.x * 256 + t;
  if (i >= NANCH) return;
  u64 v = sv[i];
  if (key_bin((u32)(v >> 32)) >= chosen) {
    u32 p = atomicAdd(&ctrl[6], 1u);
    sel[p] = v;
  }
}

// ---------------- 3) all-pairs rank of the union -> exact descending sort of top-PRE ------
// union always has n >= PRE (chosen picked so suffix >= PRE, or chosen=0 -> everything),
// so all sorted[0..PRE) slots get written.
__global__ void rank_k(const u64* __restrict__ sel, const u32* __restrict__ ctrl,
                       u64* __restrict__ sorted) {
  __shared__ u64 sj[256];
  u32 n = ctrl[6];
  int i = blockIdx.x * 256 + threadIdx.x;
  if ((u32)(blockIdx.x * 256) >= n) return;       // uniform per block
  u64 vi = ((u32)i < n) ? sel[i] : 0ULL;
  u32 cnt = 0;
  for (u32 jb = 0; jb < n; jb += 256) {
    __syncthreads();
    if (jb + threadIdx.x < n) sj[threadIdx.x] = sel[jb + threadIdx.x];
    __syncthreads();
    u32 m = min(256u, n - jb);
    #pragma unroll 8
    for (u32 j = 0; j < m; ++j) cnt += (u32)(sj[j] > vi);
  }
  if ((u32)i < n && cnt < (u32)PRE) sorted[cnt] = vi;
}

// ---------------- 4) suppression bitmask, TRANSPOSED: maskT[word_col * 6016 + row] --------
// Upper triangle only (word_col >= row's word). Writes coalesced (consecutive rows).
__global__ void mask_k(const u64* __restrict__ sorted, const float4* __restrict__ props,
                       u64* __restrict__ maskT) {
  #pragma clang fp contract(off)
  __shared__ float4 cb[64];
  int jb = blockIdx.x;
  if (jb < (int)blockIdx.y) return;   // only col-word >= row-word is ever read
  int i = blockIdx.y * 64 + threadIdx.x;
  int jj = jb * 64 + threadIdx.x;
  float4 cc = make_float4(0.f, 0.f, 0.f, 0.f);
  if (jj < PRE) {
    u64 v = sorted[jj];
    cc = props[0xFFFFu - ((u32)v & 0xFFFFu)];
  }
  cb[threadIdx.x] = cc;
  __syncthreads();
  if (i >= PRE) return;
  u64 vi = sorted[i];
  float4 b = props[0xFFFFu - ((u32)vi & 0xFFFFu)];
  float ai = (b.z - b.x + 1.0f) * (b.w - b.y + 1.0f);
  u64 bits = 0ULL;
  int jmax = min(64, PRE - jb * 64);
  for (int j = 0; j < jmax; ++j) {
    float4 c = cb[j];
    float aj = (c.z - c.x + 1.0f) * (c.w - c.y + 1.0f);
    float iw = fmaxf(fminf(b.z, c.z) - fmaxf(b.x, c.x) + 1.0f, 0.0f);
    float ih = fmaxf(fminf(b.w, c.w) - fmaxf(b.y, c.y) + 1.0f, 0.0f);
    float inter = iw * ih;
    float iou = inter / (ai + aj - inter);
    bits |= ((u64)(iou > 0.7f)) << j;
  }
  maskT[(size_t)jb * ROWSP + i] = bits;
}

// ---------------- 5) single-WG greedy scan, 2 words (128 rows) per step + fused scatter ---
// thread (g = t>>7, w = t&127, w<94) loads maskT[w][step*128 + g*16 .. +16) (consecutive
// -> dwordx4). __launch_bounds__(1024,4): exactly 1 block/CU resident -> 128-VGPR budget,
// so the 2x16-u64 buffers stay in registers (R8's 64-VGPR cap spilled them -> 197us).
// Upper-triangle skip (w >= 2*bb) is pure arithmetic (no LDS dependency).
__device__ __forceinline__ u64 rl64(u64 v, int lane) {
  u32 lo = (u32)__builtin_amdgcn_readlane((int)(u32)v, lane);
  u32 hi = (u32)__builtin_amdgcn_readlane((int)(u32)(v >> 32), lane);
  return ((u64)hi << 32) | (u64)lo;
}

__global__ void __launch_bounds__(1024, 4) nms_scan_k(const u64* __restrict__ maskT,
                                                      const u64* __restrict__ sorted,
                                                      const float4* __restrict__ props,
                                                      float* __restrict__ out) {
  __shared__ u64 Lrem[NWORDS];
  __shared__ u64 Ldiag[128][2];
  __shared__ u64 Lkb[NWORDS];
  __shared__ u64 LkA, LkB;
  __shared__ int Lstop;
  __shared__ u32 Lpre[NWORDS];
  const int t = threadIdx.x;
  const int g = t >> 7;                 // 8 groups of 16 rows
  const int w = t & 127;                // word column owned (if < 94)
  const bool loader = (w < NWORDS);
  u64 rv = 0;                           // group-partial remv for word w
  u64 B0[16], B1[16];
  int kept = 0;

#define ISSUE(bb, BUF) \
  if ((bb) < NSTEP && loader && w >= 2 * (bb)) { \
    const u64* p_ = maskT + (size_t)w * ROWSP + (bb) * 128 + g * 16; \
    _Pragma("unroll") \
    for (int k = 0; k < 16; ++k) BUF[k] = p_[k]; \
  }

  ISSUE(0, B0)
  ISSUE(1, B1)

  if (t < NWORDS) { Lrem[t] = 0ULL; Lkb[t] = 0ULL; }
  if (t == 0) Lstop = 0;
  __syncthreads();
  // invalid rows (key==0) + padding rows >= PRE -> pre-removed
  for (int r = t; r < PRE; r += 1024)
    if ((u32)(sorted[r] >> 32) == 0u)
      atomicOr((unsigned long long*)&Lrem[r >> 6], 1ULL << (r & 63));
  if (t == 0)
    atomicOr((unsigned long long*)&Lrem[NWORDS - 1],
             ~((1ULL << (PRE - (NWORDS - 1) * 64)) - 1ULL));
  __syncthreads();

#define STEP(bb, BUF) { \
    const int A_ = 2 * (bb), Bw_ = A_ + 1; \
    if (w == A_ || w == Bw_) {           /* 16 publishers */ \
      atomicOr((u32*)&Lrem[w], (u32)rv); \
      atomicOr(((u32*)&Lrem[w]) + 1, (u32)(rv >> 32)); \
      const int c_ = (w == Bw_); \
      _Pragma("unroll") \
      for (int k = 0; k < 16; ++k) { \
        int i_ = g * 16 + k; \
        if (c_ || i_ < 64) Ldiag[i_][c_] = BUF[k]; \
      } \
    } \
    __syncthreads();                     /* X: diag + final Lrem[A,B] visible */ \
    if (t < 64) { \
      u64 a0 = Ldiag[t][0], b0 = Ldiag[t][1], b1 = Ldiag[64 + t][1]; \
      u64 availA = ~Lrem[A_]; \
      u64 availB = ~Lrem[Bw_]; \
      u64 kbA = 0, kbB = 0; \
      while (availA) { \
        int i_ = __builtin_ctzll(availA); \
        kbA |= 1ULL << i_; \
        availA &= ~rl64(a0, i_) & ~((2ULL << i_) - 1ULL); /* 2<<63 wraps -> 0 */ \
        availB &= ~rl64(b0, i_); \
      } \
      while (availB) { \
        int i_ = __builtin_ctzll(availB); \
        kbB |= 1ULL << i_; \
        availB &= ~rl64(b1, i_) & ~((2ULL << i_) - 1ULL); \
      } \
      if (t == 0) { \
        Lkb[A_] = kbA; Lkb[Bw_] = kbB; LkA = kbA; LkB = kbB; \
        kept += (int)__popcll(kbA) + (int)__popcll(kbB); \
        if (kept >= POST) Lstop = 1; \
      } \
    } \
    __syncthreads();                     /* Y: kb + stop visible */ \
    if (loader && w > Bw_) { \
      u64 kA_ = LkA, kB_ = LkB; \
      _Pragma("unroll") \
      for (int k = 0; k < 16; ++k) { \
        int i_ = g * 16 + k; \
        u64 bit_ = (i_ < 64) ? (kA_ >> i_) : (kB_ >> (i_ - 64)); \
        rv |= (0ULL - (bit_ & 1ULL)) & BUF[k]; \
      } \
    } \
    ISSUE((bb) + 2, BUF)                 /* refill this buffer for step bb+2 */ \
    if (Lstop) break; }

  for (int bb = 0; bb < NSTEP; bb += 2) {
    STEP(bb, B0)
    if (bb + 1 < NSTEP) STEP(bb + 1, B1)
  }
#undef ISSUE
#undef STEP

  // ---- fused output scatter ----
  __syncthreads();                       // Lkb final everywhere
  for (int i = t; i < 12000; i += 1024) out[i] = 0.0f;
  if (t == 0) {
    u32 run = 0;
    for (int w2 = 0; w2 < NWORDS; ++w2) { Lpre[w2] = run; run += (u32)__popcll(Lkb[w2]); }
  }
  __syncthreads();                       // zero-fill + prefix done
  for (int i = t; i < PRE; i += 1024) {
    u64 word = Lkb[i >> 6];
    if ((word >> (i & 63)) & 1ULL) {
      u32 rank = Lpre[i >> 6] + (u32)__popcll(word & ((1ULL << (i & 63)) - 1ULL));
      if (rank < POST) {
        u64 v = sorted[i];
        float4 b = props[0xFFFFu - ((u32)v & 0xFFFFu)];
        out[rank * 5 + 1] = b.x;
        out[rank * 5 + 2] = b.y;
        out[rank * 5 + 3] = b.z;
        out[rank * 5 + 4] = b.w;
        out[10000 + rank] = __uint_as_float((u32)(v >> 32) & 0x7FFFFFFFu);  // col 0 stays 0
      }
    }
  }
}

extern "C" void kernel_launch(void* const* d_in, const int* in_sizes, int n_in,
                              void* d_out, int out_size, void* d_ws, size_t ws_size,
                              hipStream_t stream) {
  const float* deltas = (const float*)d_in[0];
  const float* scores = (const float*)d_in[1];
  const int* imw = (const int*)d_in[2];
  const int* imh = (const int*)d_in[3];
  char* ws = (char*)d_ws;

  float4* props   = (float4*)(ws + OFF_PROPS);
  u64*    svals   = (u64*)(ws + OFF_SV);
  u64*    sorted  = (u64*)(ws + OFF_SORTED);
  u64*    sel     = (u64*)(ws + OFF_SEL);
  u64*    maskT   = (u64*)(ws + OFF_MASKT);
  u32*    ctrl    = (u32*)(ws + OFF_CTRL);
  u32*    h1      = (u32*)(ws + OFF_H1);

  hipMemsetAsync(h1, 0, 1025 * sizeof(u32), stream);   // only the histogram needs zeroing

  decode_k<<<144, 256, 0, stream>>>(deltas, scores, imw, imh, props, svals, h1, ctrl);
  compact_k<<<144, 256, 0, stream>>>(svals, h1, ctrl, sel);
  rank_k<<<144, 256, 0, stream>>>(sel, ctrl, sorted);

  dim3 mgrid(NWORDS, NWORDS);
  mask_k<<<mgrid, 64, 0, stream>>>(sorted, props, maskT);

  nms_scan_k<<<1, 1024, 0, stream>>>(maskT, sorted, props, (float*)d_out);
}

// Round 11
// 344.499 us; speedup vs baseline: 1.2626x; 1.0681x over previous
//
#include <hip/hip_runtime.h>
#include <math.h>

typedef unsigned int u32;
typedef unsigned long long u64;

#define NANCH   36864
#define PRE     6000
#define POST    2000
#define NWORDS  94        // ceil(6000/64), even
#define ROWSP   6016      // padded rows per mask column

// ---------------- workspace layout (bytes) ----------------
#define OFF_PROPS   ((size_t)0)                    // 36864*16 = 589824
#define OFF_SV      ((size_t)589824)               // 36864*8  = 294912 -> 884736
#define OFF_SORTED  ((size_t)884736)               // 6016*8   = 48128  -> 932864
#define OFF_SEL     ((size_t)932864)               // 36864*8  = 294912 (fallback-sized) -> 1227776
#define OFF_MASKT   ((size_t)1227776)              // 94*6016*8 = 4524032 -> 5751808 (column-major: maskT[w*6016+row])
#define OFF_CTRL    ((size_t)5751808)              // 256  (ctrl[6] zeroed by decode)
#define OFF_H1      ((size_t)5752064)              // 1025*4 = 4100 (memset target)

// base anchors for base_size=16, ratios(0.5,1,2), scales(8,16,32) — np.round (banker's) applied
__device__ __constant__ float BA[9][4] = {
  {-84.f,-40.f,99.f,55.f},   {-176.f,-88.f,191.f,103.f}, {-360.f,-184.f,375.f,199.f},
  {-56.f,-56.f,71.f,71.f},   {-120.f,-120.f,135.f,135.f},{-248.f,-248.f,263.f,263.f},
  {-36.f,-80.f,51.f,95.f},   {-80.f,-168.f,95.f,183.f},  {-168.f,-344.f,183.f,359.f}};

// bin over key bits [31:13]: 1024 bins cover scores [0.5,1) exactly (monotone in key);
// bin 0 = everything below (incl. invalid key==0). Selection stays EXACT: we take the
// whole union of bins >= chosen and rank it all-pairs (keys are distinct).
__device__ __forceinline__ u32 key_bin(u32 key) {
  if (key < 0xBF000000u) return 0u;
  u32 b = ((key >> 13) - 0x5F800u) + 1u;
  return b > 1024u ? 1024u : b;
}

// ---------------- 1) decode (+ fused 1024-bin histogram; bin 0 not counted) ----------------
__global__ void decode_k(const float* __restrict__ deltas, const float* __restrict__ scores,
                         const int* __restrict__ imw_p, const int* __restrict__ imh_p,
                         float4* __restrict__ props, u64* __restrict__ sortvals,
                         u32* __restrict__ h1, u32* __restrict__ ctrl) {
  #pragma clang fp contract(off)
  if (threadIdx.x == 0) ctrl[6] = 0u;   // all blocks write 0 before compact launch
  int i = blockIdx.x * 256 + threadIdx.x;
  if (i >= NANCH) return;
  int a = i % 9;
  int pix = i / 9;
  int x = pix & 63, y = pix >> 6;

  float sc = scores[(9 + a) * 4096 + pix];
  float d0 = deltas[(a * 4 + 0) * 4096 + pix];
  float d1 = deltas[(a * 4 + 1) * 4096 + pix];
  float d2 = deltas[(a * 4 + 2) * 4096 + pix];
  float d3 = deltas[(a * 4 + 3) * 4096 + pix];

  float gx = (float)(x * 16), gy = (float)(y * 16);
  float ax1 = gx + BA[a][0], ay1 = gy + BA[a][1];
  float ax2 = gx + BA[a][2], ay2 = gy + BA[a][3];
  float aw = ax2 - ax1 + 1.0f, ah = ay2 - ay1 + 1.0f;
  float acx = ax1 + 0.5f * aw, acy = ay1 + 0.5f * ah;

  float pcx = d0 * aw + acx;
  float pcy = d1 * ah + acy;
  float pw = (float)exp((double)d2) * aw;   // f64 exp -> correctly-rounded f32
  float ph = (float)exp((double)d3) * ah;

  float imw1 = (float)imw_p[0] - 1.0f, imh1 = (float)imh_p[0] - 1.0f;
  float x1 = fminf(fmaxf(pcx - 0.5f * pw, 0.0f), imw1);
  float y1 = fminf(fmaxf(pcy - 0.5f * ph, 0.0f), imh1);
  float x2 = fminf(fmaxf(pcx + 0.5f * pw, 0.0f), imw1);
  float y2 = fminf(fmaxf(pcy + 0.5f * ph, 0.0f), imh1);
  props[i] = make_float4(x1, y1, x2, y2);

  float thresh = 16.0f * ((float)imh_p[0] / (float)imw_p[0]);
  bool keep = (x2 - x1 + 1.0f >= thresh) && (y2 - y1 + 1.0f >= thresh);
  u32 key = keep ? (__float_as_uint(sc) | 0x80000000u) : 0u;  // scores >= 0
  sortvals[i] = ((u64)key << 32) | (u64)(0xFFFFFFFFu - (u32)i); // distinct; desc order == top_k order
  u32 bin = key_bin(key);
  if (bin) atomicAdd(&h1[bin], 1u);
}

// ---------------- 2) compact the union (bins >= chosen); chosen recomputed per block ------
__global__ void compact_k(const u64* __restrict__ sv, const u32* __restrict__ h1,
                          u32* __restrict__ ctrl, u64* __restrict__ sel) {
  __shared__ u32 Lchosen;
  int t = threadIdx.x;
  if (t < 64) {                        // wave 0: recompute chosen (largest bin with suffix >= PRE)
    int l = t;
    u32 loc[16], suf[16];
    #pragma unroll
    for (int k = 0; k < 16; ++k) loc[k] = h1[1 + l * 16 + k];
    u32 acc = 0;
    #pragma unroll
    for (int k = 15; k >= 0; --k) { acc += loc[k]; suf[k] = acc; }
    u32 sfx = acc;
    for (int off = 1; off < 64; off <<= 1) {
      u32 o = __shfl_down(sfx, off);
      if (l + off < 64) sfx += o;
    }
    u32 S_above = sfx - acc;           // sum over lanes > l
    u64 mball = __ballot(suf[0] + S_above >= (u32)PRE);
    if (mball == 0ULL) { if (l == 0) Lchosen = 0u; }
    else {
      int L = 63 - __builtin_clzll(mball);
      if (l == L) {
        int kk = 0;
        for (int k = 15; k >= 0; --k)
          if (suf[k] + S_above >= (u32)PRE) { kk = k; break; }
        Lchosen = (u32)(1 + 16 * L + kk);
      }
    }
  }
  __syncthreads();
  u32 chosen = Lchosen;
  int i = blockIdx.x * 256 + t;
  if (i >= NANCH) return;
  u64 v = sv[i];
  if (key_bin((u32)(v >> 32)) >= chosen) {
    u32 p = atomicAdd(&ctrl[6], 1u);
    sel[p] = v;
  }
}

// ---------------- 3) all-pairs rank of the union -> exact descending sort of top-PRE ------
__global__ void rank_k(const u64* __restrict__ sel, const u32* __restrict__ ctrl,
                       u64* __restrict__ sorted) {
  __shared__ u64 sj[256];
  u32 n = ctrl[6];
  int i = blockIdx.x * 256 + threadIdx.x;
  if ((u32)(blockIdx.x * 256) >= n) return;       // uniform per block
  u64 vi = ((u32)i < n) ? sel[i] : 0ULL;
  u32 cnt = 0;
  for (u32 jb = 0; jb < n; jb += 256) {
    __syncthreads();
    if (jb + threadIdx.x < n) sj[threadIdx.x] = sel[jb + threadIdx.x];
    __syncthreads();
    u32 m = min(256u, n - jb);
    #pragma unroll 8
    for (u32 j = 0; j < m; ++j) cnt += (u32)(sj[j] > vi);
  }
  if ((u32)i < n && cnt < (u32)PRE) sorted[cnt] = vi;
}

// ---------------- 4) suppression bitmask, TRANSPOSED: maskT[word_col * 6016 + row] --------
__global__ void mask_k(const u64* __restrict__ sorted, const float4* __restrict__ props,
                       u64* __restrict__ maskT) {
  #pragma clang fp contract(off)
  __shared__ float4 cb[64];
  int jb = blockIdx.x;
  if (jb < (int)blockIdx.y) return;   // only col-word >= row-word is ever read
  int i = blockIdx.y * 64 + threadIdx.x;
  int jj = jb * 64 + threadIdx.x;
  float4 cc = make_float4(0.f, 0.f, 0.f, 0.f);
  if (jj < PRE) {
    u64 v = sorted[jj];
    cc = props[0xFFFFu - ((u32)v & 0xFFFFu)];
  }
  cb[threadIdx.x] = cc;
  __syncthreads();
  if (i >= PRE) return;
  u64 vi = sorted[i];
  float4 b = props[0xFFFFu - ((u32)vi & 0xFFFFu)];
  float ai = (b.z - b.x + 1.0f) * (b.w - b.y + 1.0f);
  u64 bits = 0ULL;
  int jmax = min(64, PRE - jb * 64);
  for (int j = 0; j < jmax; ++j) {
    float4 c = cb[j];
    float aj = (c.z - c.x + 1.0f) * (c.w - c.y + 1.0f);
    float iw = fmaxf(fminf(b.z, c.z) - fmaxf(b.x, c.x) + 1.0f, 0.0f);
    float ih = fmaxf(fminf(b.w, c.w) - fmaxf(b.y, c.y) + 1.0f, 0.0f);
    float inter = iw * ih;
    float iou = inter / (ai + aj - inter);
    bits |= ((u64)(iou > 0.7f)) << j;
  }
  maskT[(size_t)jb * ROWSP + i] = bits;
}

// ---------------- 5) single-WG greedy scan, ONE barrier per word + fused scatter ----------
// thread (g = t>>7, w = t&127, w<94) owns column w; per step bb it holds its 8 rows of
// chunk bb in the active buffer. The 64-row decide chain runs REDUNDANTLY on all 16 waves
// (inputs Ldiag[par]/Lrem[bb] are identical across waves) — no kb broadcast, no barrier Y.
// Publisher w==bb+1 ORs its rv into Lrem[bb+1] and writes Ldiag[1-par] from the other
// buffer (its chunk bb+1) during step bb; the single end-of-step barrier publishes both.
// Buffers: 2 x 8 u64 = 32 VGPR -> no spill at the 64-VGPR/1024-thread budget.
__device__ __forceinline__ u64 rl64(u64 v, int lane) {
  u32 lo = (u32)__builtin_amdgcn_readlane((int)(u32)v, lane);
  u32 hi = (u32)__builtin_amdgcn_readlane((int)(u32)(v >> 32), lane);
  return ((u64)hi << 32) | (u64)lo;
}

__global__ void __launch_bounds__(1024) nms_scan_k(const u64* __restrict__ maskT,
                                                   const u64* __restrict__ sorted,
                                                   const float4* __restrict__ props,
                                                   float* __restrict__ out) {
  __shared__ u64 Lrem[NWORDS];
  __shared__ u64 Ldiag[2][64];
  __shared__ u64 Lkb[NWORDS];
  __shared__ u32 Lpre[NWORDS];
  const int t = threadIdx.x;
  const int g = t >> 7;                 // row octet within current word
  const int w = t & 127;                // column owned (if < 94)
  const bool loader = (w < NWORDS);
  u64 rv = 0;                           // accumulated suppression partial for column w
  u64 B0[8], B1[8];
  int kept = 0;

#define ISSUE(bb, BUF) \
  if ((bb) < NWORDS && loader && w >= (bb)) { \
    const u64* p_ = maskT + (size_t)w * ROWSP + (bb) * 64 + g * 8; \
    _Pragma("unroll") \
    for (int k = 0; k < 8; ++k) BUF[k] = p_[k]; \
  }

  ISSUE(0, B0)
  ISSUE(1, B1)

  if (t < NWORDS) { Lrem[t] = 0ULL; Lkb[t] = 0ULL; }
  __syncthreads();
  // invalid rows (key==0) + padding rows >= PRE -> pre-removed
  for (int r = t; r < PRE; r += 1024)
    if ((u32)(sorted[r] >> 32) == 0u)
      atomicOr((unsigned long long*)&Lrem[r >> 6], 1ULL << (r & 63));
  if (t == 0)
    atomicOr((unsigned long long*)&Lrem[NWORDS - 1],
             ~((1ULL << (PRE - (NWORDS - 1) * 64)) - 1ULL));
  if (w == 0) {                          // initial diag publish for step 0 (from B0)
    #pragma unroll
    for (int k = 0; k < 8; ++k) Ldiag[0][g * 8 + k] = B0[k];
  }
  __syncthreads();

#define STEP(bb, BUF, BUFN) { \
    const int par = (bb) & 1; \
    u64 dgl = Ldiag[par][t & 63]; \
    u64 avail = ~Lrem[(bb)]; \
    u64 kb = 0; \
    while (avail) { \
      int i_ = __builtin_ctzll(avail); \
      kb |= 1ULL << i_; \
      avail &= ~rl64(dgl, i_) & ~((2ULL << i_) - 1ULL); /* 2<<63 wraps -> 0 */ \
    } \
    kept += (int)__popcll(kb); \
    if (t == 0) Lkb[(bb)] = kb; \
    if (loader && w > (bb)) { \
      _Pragma("unroll") \
      for (int k = 0; k < 8; ++k) \
        rv |= (0ULL - ((kb >> (g * 8 + k)) & 1ULL)) & BUF[k]; \
    } \
    if ((bb) + 1 < NWORDS && w == (bb) + 1) {   /* publish word bb+1 for next step */ \
      atomicOr((u32*)&Lrem[(bb) + 1], (u32)rv); \
      atomicOr(((u32*)&Lrem[(bb) + 1]) + 1, (u32)(rv >> 32)); \
      _Pragma("unroll") \
      for (int k = 0; k < 8; ++k) Ldiag[1 - par][g * 8 + k] = BUFN[k]; \
    } \
    ISSUE((bb) + 2, BUF) \
    if (kept >= POST) break; \
    __syncthreads(); }

  for (int bb = 0; bb < NWORDS; bb += 2) {
    STEP(bb, B0, B1)
    if (bb + 1 < NWORDS) STEP(bb + 1, B1, B0)
  }
#undef ISSUE
#undef STEP

  // ---- fused output scatter ----
  __syncthreads();                       // Lkb final everywhere
  for (int i = t; i < 12000; i += 1024) out[i] = 0.0f;
  if (t == 0) {
    u32 run = 0;
    for (int w2 = 0; w2 < NWORDS; ++w2) { Lpre[w2] = run; run += (u32)__popcll(Lkb[w2]); }
  }
  __syncthreads();                       // zero-fill + prefix done
  for (int i = t; i < PRE; i += 1024) {
    u64 word = Lkb[i >> 6];
    if ((word >> (i & 63)) & 1ULL) {
      u32 rank = Lpre[i >> 6] + (u32)__popcll(word & ((1ULL << (i & 63)) - 1ULL));
      if (rank < POST) {
        u64 v = sorted[i];
        float4 b = props[0xFFFFu - ((u32)v & 0xFFFFu)];
        out[rank * 5 + 1] = b.x;
        out[rank * 5 + 2] = b.y;
        out[rank * 5 + 3] = b.z;
        out[rank * 5 + 4] = b.w;
        out[10000 + rank] = __uint_as_float((u32)(v >> 32) & 0x7FFFFFFFu);  // col 0 stays 0
      }
    }
  }
}

extern "C" void kernel_launch(void* const* d_in, const int* in_sizes, int n_in,
                              void* d_out, int out_size, void* d_ws, size_t ws_size,
                              hipStream_t stream) {
  const float* deltas = (const float*)d_in[0];
  const float* scores = (const float*)d_in[1];
  const int* imw = (const int*)d_in[2];
  const int* imh = (const int*)d_in[3];
  char* ws = (char*)d_ws;

  float4* props   = (float4*)(ws + OFF_PROPS);
  u64*    svals   = (u64*)(ws + OFF_SV);
  u64*    sorted  = (u64*)(ws + OFF_SORTED);
  u64*    sel     = (u64*)(ws + OFF_SEL);
  u64*    maskT   = (u64*)(ws + OFF_MASKT);
  u32*    ctrl    = (u32*)(ws + OFF_CTRL);
  u32*    h1      = (u32*)(ws + OFF_H1);

  hipMemsetAsync(h1, 0, 1025 * sizeof(u32), stream);   // only the histogram needs zeroing

  decode_k<<<144, 256, 0, stream>>>(deltas, scores, imw, imh, props, svals, h1, ctrl);
  compact_k<<<144, 256, 0, stream>>>(svals, h1, ctrl, sel);
  rank_k<<<144, 256, 0, stream>>>(sel, ctrl, sorted);

  dim3 mgrid(NWORDS, NWORDS);
  mask_k<<<mgrid, 64, 0, stream>>>(sorted, props, maskT);

  nms_scan_k<<<1, 1024, 0, stream>>>(maskT, sorted, props, (float*)d_out);
}